// Round 10
// baseline (48.551 us; speedup 1.0000x reference)
//
#include <hip/hip_runtime.h>
#include <math.h>

// DTM layer: B=32, N=1024, D=2, M0=0.05, R=2
// R9: 2 queries per wave (same batch -> shared w[], wsum, wb; shared grid regs).
// Two interleaved Illinois/proportional searches: query B's scan fills query
// A's serial DPP-reduction + scalar-decide latency (and vice versa), attacking
// the exposed per-iteration dependency chain that kept R5-R8 flat at ~46us.
// Search: fixed 6 evals; epilogue: concave-envelope two-sided estimate
// (val(t) is concave piecewise-linear, maximized at t*; tangent intersection
// is exact when <=1 point lies inside the final bracket).

constexpr int   PER_LANE = 16;     // 1024 / 64
constexpr float M0_      = 0.05f;

template<int CTRL, int RM>
__device__ __forceinline__ float dpp_fadd(float v) {
    int moved = __builtin_amdgcn_update_dpp(0, __float_as_int(v), CTRL, RM, 0xF, true);
    return v + __int_as_float(moved);
}
template<int CTRL, int RM>
__device__ __forceinline__ float dpp_fmax(float v) {
    int moved = __builtin_amdgcn_update_dpp(0, __float_as_int(v), CTRL, RM, 0xF, true);
    return fmaxf(v, __int_as_float(moved));
}
__device__ __forceinline__ float lane63(float v) {
    return __uint_as_float((unsigned)__builtin_amdgcn_readlane(__float_as_int(v), 63));
}
__device__ __forceinline__ float wave_sum_u(float v) {
    v = dpp_fadd<0x111,0xF>(v); v = dpp_fadd<0x112,0xF>(v);
    v = dpp_fadd<0x114,0xF>(v); v = dpp_fadd<0x118,0xF>(v);
    v = dpp_fadd<0x142,0xA>(v); v = dpp_fadd<0x143,0xC>(v);
    return lane63(v);
}
// two interleaved independent chains (latency overlap)
__device__ __forceinline__ void wave_sum2_u(float& a, float& b) {
    a = dpp_fadd<0x111,0xF>(a); b = dpp_fadd<0x111,0xF>(b);
    a = dpp_fadd<0x112,0xF>(a); b = dpp_fadd<0x112,0xF>(b);
    a = dpp_fadd<0x114,0xF>(a); b = dpp_fadd<0x114,0xF>(b);
    a = dpp_fadd<0x118,0xF>(a); b = dpp_fadd<0x118,0xF>(b);
    a = dpp_fadd<0x142,0xA>(a); b = dpp_fadd<0x142,0xA>(b);
    a = dpp_fadd<0x143,0xC>(a); b = dpp_fadd<0x143,0xC>(b);
    a = lane63(a); b = lane63(b);
}
__device__ __forceinline__ void wave_max2_u(float& a, float& b) {   // >= 0
    a = dpp_fmax<0x111,0xF>(a); b = dpp_fmax<0x111,0xF>(b);
    a = dpp_fmax<0x112,0xF>(a); b = dpp_fmax<0x112,0xF>(b);
    a = dpp_fmax<0x114,0xF>(a); b = dpp_fmax<0x114,0xF>(b);
    a = dpp_fmax<0x118,0xF>(a); b = dpp_fmax<0x118,0xF>(b);
    a = dpp_fmax<0x142,0xA>(a); b = dpp_fmax<0x142,0xA>(b);
    a = dpp_fmax<0x143,0xC>(a); b = dpp_fmax<0x143,0xC>(b);
    a = lane63(a); b = lane63(b);
}
__device__ __forceinline__ void wave_sum4_u(float& a, float& b, float& c, float& d) {
    a = dpp_fadd<0x111,0xF>(a); b = dpp_fadd<0x111,0xF>(b); c = dpp_fadd<0x111,0xF>(c); d = dpp_fadd<0x111,0xF>(d);
    a = dpp_fadd<0x112,0xF>(a); b = dpp_fadd<0x112,0xF>(b); c = dpp_fadd<0x112,0xF>(c); d = dpp_fadd<0x112,0xF>(d);
    a = dpp_fadd<0x114,0xF>(a); b = dpp_fadd<0x114,0xF>(b); c = dpp_fadd<0x114,0xF>(c); d = dpp_fadd<0x114,0xF>(d);
    a = dpp_fadd<0x118,0xF>(a); b = dpp_fadd<0x118,0xF>(b); c = dpp_fadd<0x118,0xF>(c); d = dpp_fadd<0x118,0xF>(d);
    a = dpp_fadd<0x142,0xA>(a); b = dpp_fadd<0x142,0xA>(b); c = dpp_fadd<0x142,0xA>(c); d = dpp_fadd<0x142,0xA>(d);
    a = dpp_fadd<0x143,0xC>(a); b = dpp_fadd<0x143,0xC>(b); c = dpp_fadd<0x143,0xC>(c); d = dpp_fadd<0x143,0xC>(d);
    a = lane63(a); b = lane63(b); c = lane63(c); d = lane63(d);
}

// wave-uniform search state (lives in SGPRs after readlane)
struct QS { float lo, Wlo, hi, Whi; int side; bool hiV; };

__device__ __forceinline__ float qs_place(const QS& s, float tinit, float mx,
                                          float wb, int it) {
    float t;
    if (it == 0) {
        t = fmaxf(fminf(tinit, 0.90f * mx), 1e-7f * mx);
    } else if (s.hiV) {
        // proportional model through (lo, Wlo); clamps guarantee shrink
        t = fminf(s.lo * (wb / s.Wlo), s.lo + 0.90f * (s.hi - s.lo));
        t = fmaxf(t, s.lo + 0.04f * (s.hi - s.lo));
    } else {
        float frac = (wb - s.Wlo) / (s.Whi - s.Wlo);
        frac = fminf(fmaxf(frac, 0.04f), 0.96f);
        t = s.lo + (s.hi - s.lo) * frac;
    }
    return t;
}
__device__ __forceinline__ void qs_update(QS& s, float t, float sw, float wb) {
    if (sw >= wb) {
        if (s.side == 1) s.Wlo = wb - 0.5f * (wb - s.Wlo);   // Illinois decay
        s.hi = t; s.Whi = sw; s.side = 1; s.hiV = false;
    } else {
        if (s.side == -1 && !s.hiV) s.Whi = wb + 0.5f * (s.Whi - wb);
        s.lo = t; s.Wlo = sw; s.side = -1;
    }
}

__global__ __launch_bounds__(256, 4) void dtm_kernel(
    const float* __restrict__ input,   // [B, N, 2]
    const float* __restrict__ weight,  // [B, N]
    const float* __restrict__ grid,    // [N, 2]
    float* __restrict__ out)           // [B, N]
{
    const int wave = threadIdx.x >> 6;
    const int lane = threadIdx.x & 63;
    const int pid  = (blockIdx.x << 2) + wave;      // pair id in [0, 16384)
    const int b    = pid >> 9;                      // batch (512 pairs/batch)
    const int n0   = pid & 511;
    const int q0   = (b << 10) + n0;
    const int q1   = q0 + 512;                      // same batch -> shared w

    const float2 xq0 = reinterpret_cast<const float2*>(input)[q0];
    const float2 xq1 = reinterpret_cast<const float2*>(input)[q1];

    // blocked ownership: lane owns grid points [lane*16, lane*16+16)
    const int base = lane * PER_LANE;
    const float4* w4 = reinterpret_cast<const float4*>(weight + (b << 10) + base);
    const float4* g4 = reinterpret_cast<const float4*>(grid + 2 * base);

    float d2a[PER_LANE], d2b[PER_LANE], w[PER_LANE];
    float mxa = 0.f, mxb = 0.f, wsum = 0.f;
    #pragma unroll
    for (int i = 0; i < 8; ++i) {                   // 2 grid points per float4
        const float4 g = g4[i];
        float ax0 = xq0.x - g.x, ay0 = xq0.y - g.y;
        float ax1 = xq0.x - g.z, ay1 = xq0.y - g.w;
        float bx0 = xq1.x - g.x, by0 = xq1.y - g.y;
        float bx1 = xq1.x - g.z, by1 = xq1.y - g.w;
        d2a[2*i]   = ax0 * ax0 + ay0 * ay0;
        d2a[2*i+1] = ax1 * ax1 + ay1 * ay1;
        d2b[2*i]   = bx0 * bx0 + by0 * by0;
        d2b[2*i+1] = bx1 * bx1 + by1 * by1;
        mxa = fmaxf(mxa, fmaxf(d2a[2*i], d2a[2*i+1]));
        mxb = fmaxf(mxb, fmaxf(d2b[2*i], d2b[2*i+1]));
    }
    #pragma unroll
    for (int i = 0; i < 4; ++i) {
        const float4 x = w4[i];
        w[4*i+0] = x.x; w[4*i+1] = x.y; w[4*i+2] = x.z; w[4*i+3] = x.w;
        wsum += x.x + x.y + x.z + x.w;
    }

    const float total = wave_sum_u(wsum);           // shared (same batch)
    const float wb    = M0_ * total;
    wave_max2_u(mxa, mxb);

    // analytic warm start: grid ~ N(0,I2) => W(t) ~ total*exp(-r2/2)*t/2
    const float ra2 = xq0.x * xq0.x + xq0.y * xq0.y;
    const float rb2 = xq1.x * xq1.x + xq1.y * xq1.y;
    const float tia = 0.31415927f * __expf(0.5f * ra2);
    const float tib = 0.31415927f * __expf(0.5f * rb2);

    // ---- fixed 6-eval bracket refinement, two interleaved searches
    QS A  = {0.f, 0.f, mxa, total, 0, true};
    QS Bs = {0.f, 0.f, mxb, total, 0, true};
    #pragma unroll
    for (int it = 0; it < 6; ++it) {
        const float ta = qs_place(A,  tia, mxa, wb, it);
        const float tb = qs_place(Bs, tib, mxb, wb, it);
        float sa = 0.f, sb = 0.f;
        #pragma unroll
        for (int k = 0; k < PER_LANE; ++k) {
            const float wk = w[k];
            sa += (d2a[k] <= ta) ? wk : 0.f;
            sb += (d2b[k] <= tb) ? wk : 0.f;
        }
        wave_sum2_u(sa, sb);                        // uniform
        qs_update(A,  ta, sa, wb);
        qs_update(Bs, tb, sb, wb);
    }

    // ---- two-sided epilogue for both queries (one fused pass)
    float Ala = 0.f, Sla = 0.f, Aha = 0.f, Sha = 0.f;
    float Alb = 0.f, Slb = 0.f, Ahb = 0.f, Shb = 0.f;
    #pragma unroll
    for (int k = 0; k < PER_LANE; ++k) {
        const float wk = w[k];
        const float da = d2a[k], db = d2b[k];
        const float dwa = da * wk, dwb = db * wk;
        Aha += (da < A.hi)  ? dwa : 0.f;
        Sha += (da < A.hi)  ? wk  : 0.f;
        Ala += (da < A.lo)  ? dwa : 0.f;
        Sla += (da < A.lo)  ? wk  : 0.f;
        Ahb += (db < Bs.hi) ? dwb : 0.f;
        Shb += (db < Bs.hi) ? wk  : 0.f;
        Alb += (db < Bs.lo) ? dwb : 0.f;
        Slb += (db < Bs.lo) ? wk  : 0.f;
    }
    wave_sum4_u(Ala, Sla, Aha, Sha);
    wave_sum4_u(Alb, Slb, Ahb, Shb);

    // concave-envelope estimate per query
    const float dSa = Sha - Sla;
    float tha = (dSa > 0.f) ? (Aha - Ala) / dSa : A.hi;
    tha = fminf(fmaxf(tha, A.lo), A.hi);
    const float vhata = fminf(Ala + tha * (wb - Sla), Aha + tha * (wb - Sha));
    const float vmaxa = fmaxf(Ala + A.lo * (wb - Sla), Aha + A.hi * (wb - Sha));
    const float vala  = 0.5f * (vhata + vmaxa) / wb;

    const float dSb = Shb - Slb;
    float thb = (dSb > 0.f) ? (Ahb - Alb) / dSb : Bs.hi;
    thb = fminf(fmaxf(thb, Bs.lo), Bs.hi);
    const float vhatb = fminf(Alb + thb * (wb - Slb), Ahb + thb * (wb - Shb));
    const float vmaxb = fmaxf(Alb + Bs.lo * (wb - Slb), Ahb + Bs.hi * (wb - Shb));
    const float valb  = 0.5f * (vhatb + vmaxb) / wb;

    if (lane == 0) {
        out[q0] = sqrtf(fmaxf(vala, 0.f));
        out[q1] = sqrtf(fmaxf(valb, 0.f));
    }
}

extern "C" void kernel_launch(void* const* d_in, const int* in_sizes, int n_in,
                              void* d_out, int out_size, void* d_ws, size_t ws_size,
                              hipStream_t stream) {
    const float* input  = (const float*)d_in[0];   // [32,1024,2]
    const float* weight = (const float*)d_in[1];   // [32,1024]
    const float* grid   = (const float*)d_in[2];   // [1024,2]
    float* out = (float*)d_out;                    // [32,1024]

    // 16384 query pairs, 1 pair per wave, 4 waves per block
    dim3 blk(256);
    dim3 grd(4096);
    hipLaunchKernelGGL(dtm_kernel, grd, blk, 0, stream,
                       input, weight, grid, out);
}

// Round 12
// 46.955 us; speedup vs baseline: 1.0340x; 1.0340x over previous
//
#include <hip/hip_runtime.h>
#include <math.h>

// DTM layer: B=32, N=1024, D=2, M0=0.05, R=2
// out = sqrt( (A_strict(t*) + t*(wb - S_strict(t*)))/wb ), t* = weighted
// 5%-quantile of d2, wb = 0.05*sum_b(w).
// R11 = R10 structure (round-trip minimal) + tail fixes:
//  - seed t0 = 0.1*pi*exp(min(r2/2, 3)): the Gaussian small-t model explodes
//    for far queries (r2>6); capped seed ~6.3 sits inside the true tail
//    quantile range (|x|-r_c)^2 in [1,9]  -> ladder brackets tails too.
//  - ladder {0.5, 1.2, 2.88}*t0 (S-only, fused into pass0 with wsum+max);
//  - 4 adaptive refinements (S-only scans, one DPP chain each);
//  - one fused two-sided epilogue pass for A at lo,hi; concave-envelope
//    output (val(t) concave piecewise-linear, max at t*; tangent-intersection
//    estimate is exact when <=1 point inside the final bracket).
// Dependent round-trips: 6 (R8: ~8).

constexpr int   PER_LANE = 16;     // 1024 / 64
constexpr float M0_      = 0.05f;

template<int CTRL, int RM>
__device__ __forceinline__ float dpp_fadd(float v) {
    int moved = __builtin_amdgcn_update_dpp(0, __float_as_int(v), CTRL, RM, 0xF, true);
    return v + __int_as_float(moved);
}
template<int CTRL, int RM>
__device__ __forceinline__ float dpp_fmax(float v) {
    int moved = __builtin_amdgcn_update_dpp(0, __float_as_int(v), CTRL, RM, 0xF, true);
    return fmaxf(v, __int_as_float(moved));
}
__device__ __forceinline__ float lane63(float v) {
    return __uint_as_float((unsigned)__builtin_amdgcn_readlane(__float_as_int(v), 63));
}

// 4 interleaved sum chains + 1 max chain, one latency depth
__device__ __forceinline__ void wave_red5(float& a, float& b, float& c,
                                          float& d, float& m) {
#define STG(CT, RM) \
    a = dpp_fadd<CT,RM>(a); b = dpp_fadd<CT,RM>(b); c = dpp_fadd<CT,RM>(c); \
    d = dpp_fadd<CT,RM>(d); m = dpp_fmax<CT,RM>(m);
    STG(0x111,0xF) STG(0x112,0xF) STG(0x114,0xF)
    STG(0x118,0xF) STG(0x142,0xA) STG(0x143,0xC)
#undef STG
    a = lane63(a); b = lane63(b); c = lane63(c); d = lane63(d); m = lane63(m);
}
__device__ __forceinline__ float wave_sum1(float v) {
    v = dpp_fadd<0x111,0xF>(v); v = dpp_fadd<0x112,0xF>(v);
    v = dpp_fadd<0x114,0xF>(v); v = dpp_fadd<0x118,0xF>(v);
    v = dpp_fadd<0x142,0xA>(v); v = dpp_fadd<0x143,0xC>(v);
    return lane63(v);
}
__device__ __forceinline__ void wave_sum2_u(float& a, float& b) {
    a = dpp_fadd<0x111,0xF>(a); b = dpp_fadd<0x111,0xF>(b);
    a = dpp_fadd<0x112,0xF>(a); b = dpp_fadd<0x112,0xF>(b);
    a = dpp_fadd<0x114,0xF>(a); b = dpp_fadd<0x114,0xF>(b);
    a = dpp_fadd<0x118,0xF>(a); b = dpp_fadd<0x118,0xF>(b);
    a = dpp_fadd<0x142,0xA>(a); b = dpp_fadd<0x142,0xA>(b);
    a = dpp_fadd<0x143,0xC>(a); b = dpp_fadd<0x143,0xC>(b);
    a = lane63(a); b = lane63(b);
}

__global__ __launch_bounds__(256) void dtm_kernel(
    const float* __restrict__ input,   // [B, N, 2]
    const float* __restrict__ weight,  // [B, N]
    const float* __restrict__ grid,    // [N, 2]
    float* __restrict__ out)           // [B, N]
{
    const int wave = threadIdx.x >> 6;
    const int lane = threadIdx.x & 63;
    const int q    = (blockIdx.x << 2) + wave;
    const int b    = q >> 10;

    const float2 xq = reinterpret_cast<const float2*>(input)[q];

    // capped analytic seed (tail-safe): t0 <= 0.314*e^3 ~ 6.3
    const float r2q = xq.x * xq.x + xq.y * xq.y;
    const float t0  = 0.31415927f * __expf(fminf(0.5f * r2q, 3.0f));
    const float t1  = 0.50f * t0, t2 = 1.20f * t0, t3 = 2.88f * t0;

    const int base = lane * PER_LANE;
    const float4* w4 = reinterpret_cast<const float4*>(weight + (b << 10) + base);
    const float4* g4 = reinterpret_cast<const float4*>(grid + 2 * base);

    float w[PER_LANE], d2[PER_LANE];
    float wsum = 0.f;
    #pragma unroll
    for (int i = 0; i < 4; ++i) {
        const float4 x = w4[i];
        w[4*i+0] = x.x; w[4*i+1] = x.y; w[4*i+2] = x.z; w[4*i+3] = x.w;
        wsum += x.x + x.y + x.z + x.w;
    }

    // ---- pass0: d2 + 3 S-only ladder probes + max, fused; ONE reduction
    float S1 = 0.f, S2 = 0.f, S3 = 0.f, mx = 0.f;
    #pragma unroll
    for (int i = 0; i < 8; ++i) {                   // 2 grid points per float4
        const float4 g = g4[i];
        #pragma unroll
        for (int j = 0; j < 2; ++j) {
            const int k  = 2*i + j;
            const float gx = j ? g.z : g.x;
            const float gy = j ? g.w : g.y;
            const float dx = xq.x - gx, dy = xq.y - gy;
            const float dk = dx * dx + dy * dy;
            d2[k] = dk;
            const float wk = w[k];
            mx = fmaxf(mx, dk);
            S1 += (dk <= t1) ? wk : 0.f;
            S2 += (dk <= t2) ? wk : 0.f;
            S3 += (dk <= t3) ? wk : 0.f;
        }
    }
    wave_red5(wsum, S1, S2, S3, mx);                // round-trip 1
    const float total = wsum;
    const float wb    = M0_ * total;

    // ---- init bracket from ladder (wave-uniform scalars)
    float lo, Wlo, hi, Whi;
    bool hiP;                                        // hi probed (Whi real)?
    if (S1 >= wb)      { lo = 0.f; Wlo = 0.f; hi = t1; Whi = S1;    hiP = true;  }
    else if (S2 >= wb) { lo = t1;  Wlo = S1;  hi = t2; Whi = S2;    hiP = true;  }
    else if (S3 >= wb) { lo = t2;  Wlo = S2;  hi = t3; Whi = S3;    hiP = true;  }
    else               { lo = t3;  Wlo = S3;  hi = mx; Whi = total; hiP = false; }

    // ---- 4 adaptive refinements (S-only), round-trips 2..5
    #pragma unroll
    for (int it = 0; it < 4; ++it) {
        float t;
        if (!hiP) {
            // proportional model through (lo, Wlo); clamps guarantee shrink
            t = fminf(lo * (wb / Wlo), lo + 0.90f * (hi - lo));
            t = fmaxf(t, lo + 0.08f * (hi - lo));
        } else {
            float fr = (wb - Wlo) / (Whi - Wlo);
            fr = fminf(fmaxf(fr, 0.06f), 0.94f);
            t = lo + (hi - lo) * fr;
        }
        float sv = 0.f;
        #pragma unroll
        for (int k = 0; k < PER_LANE; ++k)
            sv += (d2[k] <= t) ? w[k] : 0.f;
        const float s = wave_sum1(sv);
        if (s >= wb) { hi = t; Whi = s; hiP = true; }
        else         { lo = t; Wlo = s; }
    }

    // ---- two-sided epilogue: A at lo and hi in one pass (round-trip 6)
    float Alv = 0.f, Ahv = 0.f;
    #pragma unroll
    for (int k = 0; k < PER_LANE; ++k) {
        const float dk = d2[k];
        const float dw = dk * w[k];
        Ahv += (dk < hi) ? dw : 0.f;
        Alv += (dk < lo) ? dw : 0.f;
    }
    wave_sum2_u(Alv, Ahv);

    // concave-envelope estimate (S at endpoints = Wlo/Whi from the search)
    float val;
    if (hiP) {
        float that = (Ahv - Alv) / (Whi - Wlo);      // Whi>=wb>Wlo => >0
        that = fminf(fmaxf(that, lo), hi);
        const float vL   = Alv + that * (wb - Wlo);  // tangent from lo
        const float vH   = Ahv + that * (wb - Whi);  // tangent from hi
        const float vhat = fminf(vL, vH);            // upper bound, wb*val
        const float vmax = fmaxf(Alv + lo * (wb - Wlo),
                                 Ahv + hi * (wb - Whi));   // lower bound
        val = 0.5f * (vhat + vmax) / wb;
    } else {                                          // never bracketed (rare)
        val = (Alv + 0.5f * (lo + hi) * (wb - Wlo)) / wb;
    }

    if (lane == 0) out[q] = sqrtf(fmaxf(val, 0.f));
}

extern "C" void kernel_launch(void* const* d_in, const int* in_sizes, int n_in,
                              void* d_out, int out_size, void* d_ws, size_t ws_size,
                              hipStream_t stream) {
    const float* input  = (const float*)d_in[0];   // [32,1024,2]
    const float* weight = (const float*)d_in[1];   // [32,1024]
    const float* grid   = (const float*)d_in[2];   // [1024,2]
    float* out = (float*)d_out;                    // [32,1024]

    const int total_q = 32 * 1024;                 // B*N
    dim3 blk(256);                                 // 4 waves/block, 1 query/wave
    dim3 grd(total_q / 4);                         // 8192 blocks
    hipLaunchKernelGGL(dtm_kernel, grd, blk, 0, stream,
                       input, weight, grid, out);
}